// Round 6
// baseline (108.939 us; speedup 1.0000x reference)
//
#include <hip/hip_runtime.h>

// RelativePositionAttention collapses algebraically:
//   softmax over w of (Q[t]-K[w]) is Q-independent; sum_w softmax = 1, so
//   out_heads = Vh exactly. => result = values @ M^T with
//   M[i][j] = sum_{h,d} Wp[i*EH + d*H + h] * Wv[(h*E + d)*E + j]  (256x256).
// LayerNorm / Wq / Wk / position_embeddings are dead code.
//
// R6: single dispatch (R4 showed grid.sync ~60us -> never again; R5 showed
// redundant Wv reads are per-CU-L2-BW death). 64 blocks x 1024 thr, 1/CU:
//  Phase A: block builds M rows i0..i0+3 in LDS. Each thread computes ALL 4
//    rows from each Wv float4 (1 MB unique loads/block, no redundancy);
//    k split 16-ways across waves; LDS reduce. No global MT, no d_ws.
//  Phase B: wave kc keeps M[4][16-j-chunk] in registers; values staged in
//    LDS (pad 257: scalar stage conflict-free, compute reads 2-way=free)
//    per 64-row batch; LDS kc-reduce; coalesced-ish 16B stores.

constexpr int E  = 256;
constexpr int H  = 4;
constexpr int EH = E * H;   // 1024
constexpr int BT = 512;     // B*T

union SMem {
    struct {                          // phase A: 83,968 B
        float sWp[4][EH];             // 16 KB  Wp rows i0..i0+3
        float sAcc[16][4][264];       // 66 KB  per-wave partials (pad 264: 2-way reads)
    } a;
    struct {                          // phase B: 86,400 B
        float sM[4][264];             // 4.2 KB M rows (overlaps dead sWp)
        float sV[64][257];            // 64 KB  values batch (pad 257: odd -> free reads)
        float sP[16][64][4];          // 16 KB  per-wave partials
    } b;
};

__global__ __launch_bounds__(1024) void fused_kernel(
    const float* __restrict__ values, const float* __restrict__ Wv,
    const float* __restrict__ Wp, float* __restrict__ out)
{
    __shared__ SMem sm;
    const int tid  = threadIdx.x;
    const int lane = tid & 63;
    const int kc   = tid >> 6;        // wave id 0..15 = k-chunk / j-chunk
    const int i0   = blockIdx.x * 4;  // this block's 4 M-rows / out-columns

    // ---------------- phase A: M rows i0..i0+3 -> LDS ----------------
    ((float4*)sm.a.sWp)[tid] = ((const float4*)(Wp + i0 * EH))[tid]; // 16KB coalesced
    __syncthreads();

    {
        const int j0 = lane * 4;      // j-quad
        float4 a0 = {0,0,0,0}, a1 = {0,0,0,0}, a2 = {0,0,0,0}, a3 = {0,0,0,0};
        #pragma unroll
        for (int h = 0; h < H; ++h) {
            // d-range [kc*16, kc*16+16): wave-exclusive -> no redundant loads
            const float* __restrict__ p = Wv + (h * E + kc * 16) * E + j0;
            #pragma unroll
            for (int dd = 0; dd < 16; ++dd) {
                const float4 wv = *(const float4*)(p + dd * E);   // 16B coalesced, unique
                const int   kk  = (kc * 16 + dd) * 4 + h;
                const float w0 = sm.a.sWp[0][kk], w1 = sm.a.sWp[1][kk];
                const float w2 = sm.a.sWp[2][kk], w3 = sm.a.sWp[3][kk]; // wave-uniform -> bcast
                a0.x += w0*wv.x; a0.y += w0*wv.y; a0.z += w0*wv.z; a0.w += w0*wv.w;
                a1.x += w1*wv.x; a1.y += w1*wv.y; a1.z += w1*wv.z; a1.w += w1*wv.w;
                a2.x += w2*wv.x; a2.y += w2*wv.y; a2.z += w2*wv.z; a2.w += w2*wv.w;
                a3.x += w3*wv.x; a3.y += w3*wv.y; a3.z += w3*wv.z; a3.w += w3*wv.w;
            }
        }
        *(float4*)&sm.a.sAcc[kc][0][j0] = a0;   // stride-16B b128: conflict-free
        *(float4*)&sm.a.sAcc[kc][1][j0] = a1;
        *(float4*)&sm.a.sAcc[kc][2][j0] = a2;
        *(float4*)&sm.a.sAcc[kc][3][j0] = a3;
    }
    __syncthreads();

    {   // reduce 16 k-chunks -> sM[ii][j]. banks = (8*ii + j)%32 -> 2-way=free
        const int ii = tid & 3, j = tid >> 2;   // j 0..255
        float v = 0.f;
        #pragma unroll
        for (int c = 0; c < 16; ++c) v += sm.a.sAcc[c][ii][j];
        sm.b.sM[ii][j] = v;                     // overlaps sWp (dead after sync)
    }
    __syncthreads();

    // ---------------- phase B: out[:, i0..i0+3] = values . M^T ----------------
    // wave kc owns j in [kc*16, +16); pin M[4][16] in VGPRs (wave-uniform bcast reads)
    float4 m4[4][4];
    #pragma unroll
    for (int ii = 0; ii < 4; ++ii)
        #pragma unroll
        for (int q = 0; q < 4; ++q)
            m4[ii][q] = *(const float4*)&sm.b.sM[ii][kc * 16 + q * 4]; // aligned, bcast

    for (int rb = 0; rb < 8; ++rb) {            // 8 batches of 64 rows
        // stage: scalar coalesced global reads, LDS writes banks=(r+c)%32 free
        #pragma unroll
        for (int p = 0; p < 16; ++p) {
            const int f = p * 1024 + tid;       // 0..16383
            const int r = f >> 8, c = f & 255;
            sm.b.sV[r][c] = values[(rb * 64 + r) * E + c];
        }
        __syncthreads();

        // lane = r_local; reads sV[lane][kc*16+j]: banks=(lane+j)%32 -> 2-way free
        float4 acc = {0,0,0,0};
        const float* __restrict__ vrow = &sm.b.sV[lane][kc * 16];
        #pragma unroll
        for (int q = 0; q < 4; ++q) {
            const float v0 = vrow[q*4+0], v1 = vrow[q*4+1];
            const float v2 = vrow[q*4+2], v3 = vrow[q*4+3];
            acc.x += v0*m4[0][q].x; acc.y += v0*m4[1][q].x; acc.z += v0*m4[2][q].x; acc.w += v0*m4[3][q].x;
            acc.x += v1*m4[0][q].y; acc.y += v1*m4[1][q].y; acc.z += v1*m4[2][q].y; acc.w += v1*m4[3][q].y;
            acc.x += v2*m4[0][q].z; acc.y += v2*m4[1][q].z; acc.z += v2*m4[2][q].z; acc.w += v2*m4[3][q].z;
            acc.x += v3*m4[0][q].w; acc.y += v3*m4[1][q].w; acc.z += v3*m4[2][q].w; acc.w += v3*m4[3][q].w;
        }
        *(float4*)&sm.b.sP[kc][lane][0] = acc;  // stride-16B b128: conflict-free
        __syncthreads();

        // reduce over kc + store (waves 0..3 only; banks = tid%32 -> 2-way free)
        if (tid < 256) {
            const int ii = tid & 3, r = tid >> 2;   // r 0..63
            float v = 0.f;
            #pragma unroll
            for (int c = 0; c < 16; ++c) v += sm.b.sP[c][r][ii];
            out[(rb * 64 + r) * E + i0 + ii] = v;   // 16B segments
        }
        // next iteration's post-stage __syncthreads fences sV/sP reuse
    }
}

extern "C" void kernel_launch(void* const* d_in, const int* in_sizes, int n_in,
                              void* d_out, int out_size, void* d_ws, size_t ws_size,
                              hipStream_t stream) {
    // inputs: 0 pos_emb(unused) 1 values 2 ln_w 3 ln_b 4 Wq 5 Wk 6 Wv 7 Wp
    const float* values = (const float*)d_in[1];
    const float* Wv     = (const float*)d_in[6];
    const float* Wp     = (const float*)d_in[7];
    float*       out    = (float*)d_out;
    // d_ws intentionally unused — M lives in LDS.

    fused_kernel<<<E / 4, 1024, 0, stream>>>(values, Wv, Wp, out);
}

// Round 7
// 79.337 us; speedup vs baseline: 1.3731x; 1.3731x over previous
//
#include <hip/hip_runtime.h>

// RelativePositionAttention collapses algebraically:
//   softmax over w of (Q[t]-K[w]) is Q-independent; sum_w softmax = 1, so
//   out_heads = Vh exactly. => result = values @ M^T with
//   M[i][j] = sum_{h,d} Wp[i*EH + d*H + h] * Wv[(h*E + d)*E + j]  (256x256).
// LayerNorm / Wq / Wk / position_embeddings are dead code.
//
// R7: lessons: grid.sync = 60us (R4, never); 64-block grids choke on per-CU
// L2 BW (R5/R6). So: 2 dispatches, 256 blocks each, no memset/atomics.
//  - build: block = (i-group 4 rows) x (j-group 64 cols), full k=1024
//    in-block: wave kc + lane dsub own 4 d's x 4 h; shfl_xor dsub-reduce,
//    LDS kc-reduce, plain stores. 256+16 KB L2 per block.
//  - apply: R3's kernel verbatim (256 blocks, float4, LDS j-reduce).

constexpr int E  = 256;
constexpr int H  = 4;
constexpr int EH = E * H;   // 1024
constexpr int BT = 512;     // B*T

// grid 256: bx -> i0=(bx>>2)*4, j0=(bx&3)*64. 1024 thr = 16 waves.
// thread: kc=tid>>6 (wave), dsub=(lane>>4), jq=lane&15 -> owns
// d in [kc*16+dsub*4, +4), j-quad j0+jq*4, accumulates all 4 i-rows.
__global__ __launch_bounds__(1024) void build_m_kernel(
    const float* __restrict__ Wv, const float* __restrict__ Wp,
    float* __restrict__ MT)
{
    const int tid  = threadIdx.x;
    const int lane = tid & 63;
    const int kc   = tid >> 6;          // 0..15
    const int dsub = lane >> 4;         // 0..3
    const int jq   = lane & 15;         // 0..15
    const int i0   = (blockIdx.x >> 2) * 4;
    const int j0   = (blockIdx.x & 3) * 64;

    __shared__ float sWp[4][EH];        // 16 KB: Wp rows i0..i0+3
    ((float4*)sWp)[tid] = ((const float4*)(Wp + i0 * EH))[tid];  // coalesced
    __syncthreads();

    const int dbase = kc * 16 + dsub * 4;
    const int jj    = j0 + jq * 4;

    float4 a0 = {0,0,0,0}, a1 = {0,0,0,0}, a2 = {0,0,0,0}, a3 = {0,0,0,0};
    #pragma unroll
    for (int h = 0; h < H; ++h) {
        const float* __restrict__ p = Wv + (h * E + dbase) * E + jj;
        #pragma unroll
        for (int it = 0; it < 4; ++it) {
            const float4 wv = *(const float4*)(p + it * E);  // 16 indep loads/thread
            const int    k  = (dbase + it) * 4 + h;
            const float w0 = sWp[0][k], w1 = sWp[1][k];      // 2 banks, 2-way = free
            const float w2 = sWp[2][k], w3 = sWp[3][k];
            a0.x += w0*wv.x; a0.y += w0*wv.y; a0.z += w0*wv.z; a0.w += w0*wv.w;
            a1.x += w1*wv.x; a1.y += w1*wv.y; a1.z += w1*wv.z; a1.w += w1*wv.w;
            a2.x += w2*wv.x; a2.y += w2*wv.y; a2.z += w2*wv.z; a2.w += w2*wv.w;
            a3.x += w3*wv.x; a3.y += w3*wv.y; a3.z += w3*wv.z; a3.w += w3*wv.w;
        }
    }

    // reduce over dsub (lanes ^16, ^32) in-register
    #pragma unroll
    for (int mask = 16; mask < 64; mask <<= 1) {
        a0.x += __shfl_xor(a0.x, mask); a0.y += __shfl_xor(a0.y, mask);
        a0.z += __shfl_xor(a0.z, mask); a0.w += __shfl_xor(a0.w, mask);
        a1.x += __shfl_xor(a1.x, mask); a1.y += __shfl_xor(a1.y, mask);
        a1.z += __shfl_xor(a1.z, mask); a1.w += __shfl_xor(a1.w, mask);
        a2.x += __shfl_xor(a2.x, mask); a2.y += __shfl_xor(a2.y, mask);
        a2.z += __shfl_xor(a2.z, mask); a2.w += __shfl_xor(a2.w, mask);
        a3.x += __shfl_xor(a3.x, mask); a3.y += __shfl_xor(a3.y, mask);
        a3.z += __shfl_xor(a3.z, mask); a3.w += __shfl_xor(a3.w, mask);
    }

    __shared__ float sAcc[16][4][64];   // 16 KB: [kc][ii][j-local]
    if (lane < 16) {                    // lanes 0..15: b128 writes, conflict-free
        *(float4*)&sAcc[kc][0][jq * 4] = a0;
        *(float4*)&sAcc[kc][1][jq * 4] = a1;
        *(float4*)&sAcc[kc][2][jq * 4] = a2;
        *(float4*)&sAcc[kc][3][jq * 4] = a3;
    }
    __syncthreads();

    if (tid < 256) {                    // reduce 16 kc-partials, store
        const int ii = tid & 3, jl = tid >> 2;   // jl 0..63
        float v = 0.f;
        #pragma unroll
        for (int c = 0; c < 16; ++c) v += sAcc[c][ii][jl];  // bank=jl%32, 2-way free
        MT[(j0 + jl) * E + i0 + ii] = v;         // 16B segments, no atomic
    }
}

// out[r,e] = sum_j values[r,j] * MT[j*E + e]   (R3's proven apply)
// grid 256 x 1024 thr. thread: e0=(tid&63)*4 (float4), rr=(tid>>6)&1 (row),
// jc=tid>>7 (j-chunk of 32). LDS j-reduce, coalesced stores.
__global__ __launch_bounds__(1024) void apply_kernel(
    const float* __restrict__ values, const float* __restrict__ MT,
    float* __restrict__ out)
{
    const int tid = threadIdx.x;
    const int e0  = (tid & 63) * 4;
    const int rr  = (tid >> 6) & 1;
    const int jc  = tid >> 7;            // 0..7
    const int r0  = blockIdx.x * 2;

    __shared__ float sv[2][E];
    if (tid < 2 * E) sv[tid >> 8][tid & 255] = values[r0 * E + tid];
    __syncthreads();

    float4 acc = {0,0,0,0};
    #pragma unroll
    for (int jj = 0; jj < 32; ++jj) {
        const int    j = jc * 32 + jj;
        const float4 m = *(const float4*)&MT[j * E + e0];    // 16B coalesced
        const float  s = sv[rr][j];                          // LDS broadcast
        acc.x += s * m.x; acc.y += s * m.y; acc.z += s * m.z; acc.w += s * m.w;
    }

    __shared__ float sAc2[8][2][E];      // 16 KB
    *(float4*)&sAc2[jc][rr][e0] = acc;
    __syncthreads();

    if (tid < 2 * E) {
        const int r_idx = tid >> 8, e = tid & 255;
        float v = 0.f;
        #pragma unroll
        for (int c = 0; c < 8; ++c) v += sAc2[c][r_idx][e];
        out[(r0 + r_idx) * E + e] = v;                       // coalesced
    }
}

extern "C" void kernel_launch(void* const* d_in, const int* in_sizes, int n_in,
                              void* d_out, int out_size, void* d_ws, size_t ws_size,
                              hipStream_t stream) {
    // inputs: 0 pos_emb(unused) 1 values 2 ln_w 3 ln_b 4 Wq 5 Wk 6 Wv 7 Wp
    const float* values = (const float*)d_in[1];
    const float* Wv     = (const float*)d_in[6];
    const float* Wp     = (const float*)d_in[7];
    float*       out    = (float*)d_out;
    float*       MT     = (float*)d_ws;  // E*E floats; fully overwritten by build

    build_m_kernel<<<256, 1024, 0, stream>>>(Wv, Wp, MT);
    apply_kernel<<<BT / 2, 1024, 0, stream>>>(values, MT, out);
}